// Round 1
// baseline (206.934 us; speedup 1.0000x reference)
//
#include <hip/hip_runtime.h>
#include <math.h>

// ---------------------------------------------------------------------------
// HybridClassifier: quantum patch filter (4-qubit RY encode + fixed 16x16
// unitary + PauliZ expectations) -> fc1(784->120)+relu -> fc2(120->84)+relu
// -> fc3(84->1) -> analytic hybrid head -> [p, 1-p].
// Batch = 8192. All fp32.
// ---------------------------------------------------------------------------

#define BATCH   8192
#define NPATCH  196

// ===========================================================================
// K1: quantum filter. One thread per (batch, patch). 6272 blocks x 256.
// feats[b, p*4 + w] = <Z_w> of U |RY(x_patch)>.
// ===========================================================================
__global__ __launch_bounds__(256) void qfilter_kernel(
    const float* __restrict__ x, const float* __restrict__ U,
    float* __restrict__ feats)
{
    int gid = blockIdx.x * 256 + threadIdx.x;
    if (gid >= BATCH * NPATCH) return;
    int b = gid / NPATCH;
    int p = gid - b * NPATCH;
    int pr = p / 14;
    int pc = p - pr * 14;
    const float* xr = x + b * 784 + pr * 56 + pc * 2;
    float x0 = xr[0], x1 = xr[1], x2 = xr[28], x3 = xr[29];

    float s0, c0, s1, c1, s2, c2, s3, c3;
    __sincosf(0.5f * x0, &s0, &c0);
    __sincosf(0.5f * x1, &s1, &c1);
    __sincosf(0.5f * x2, &s2, &c2);
    __sincosf(0.5f * x3, &s3, &c3);

    // psi[i8+j4+k2+l] = a0[i]a1[j]a2[k]a3[l], wire0 = MSB, a[0]=cos a[1]=sin
    float t01[4] = {c0 * c1, c0 * s1, s0 * c1, s0 * s1};
    float t23[4] = {c2 * c3, c2 * s3, s2 * c3, s2 * s3};
    float psi[16];
#pragma unroll
    for (int i = 0; i < 16; ++i) psi[i] = t01[i >> 2] * t23[i & 3];

    // phi = U @ psi ; q = phi^2 ; meas[w] = sum_i q_i * (1 - 2*bit_w(i))
    float m0 = 0.f, m1 = 0.f, m2 = 0.f, m3 = 0.f;
#pragma unroll
    for (int i = 0; i < 16; ++i) {
        float acc = 0.f;
#pragma unroll
        for (int j = 0; j < 16; ++j)
            acc = fmaf(U[i * 16 + j], psi[j], acc);  // uniform -> s_load
        float q = acc * acc;
        m0 += (i & 8) ? -q : q;
        m1 += (i & 4) ? -q : q;
        m2 += (i & 2) ? -q : q;
        m3 += (i & 1) ? -q : q;
    }
    float4 o;
    o.x = m0; o.y = m1; o.z = m2; o.w = m3;
    *reinterpret_cast<float4*>(feats + b * 784 + p * 4) = o;
}

// ===========================================================================
// K2: fc1 GEMM  h1 = relu(feats @ w1^T + b1).  M=8192 K=784 N=120.
// BM=64, BN=64 (two N-blocks cover 120+8pad), BK=56, 256 threads,
// 4x4 register tile per thread, float4 LDS reads (rows padded to 60 floats).
// grid = (8192/64) * 2 = 256 blocks.
// ===========================================================================
__global__ __launch_bounds__(256) void fc1_kernel(
    const float* __restrict__ feats, const float* __restrict__ w1,
    const float* __restrict__ b1, float* __restrict__ h1)
{
    __shared__ float As[64 * 60];
    __shared__ float Bs[64 * 60];
    const int tid  = threadIdx.x;
    const int mblk = blockIdx.x >> 1;
    const int n0   = (blockIdx.x & 1) * 64;
    const int m0   = mblk * 64;
    const int tm   = tid & 15;
    const int tn   = tid >> 4;

    float acc[4][4];
#pragma unroll
    for (int i = 0; i < 4; ++i)
#pragma unroll
        for (int j = 0; j < 4; ++j) acc[i][j] = 0.f;

    for (int k0 = 0; k0 < 784; k0 += 56) {
        // stage A tile: 64 rows x 56 k  (896 float4)
        for (int t = tid; t < 896; t += 256) {
            int r  = t / 14;
            int kq = t - r * 14;
            float4 v = *reinterpret_cast<const float4*>(
                feats + (size_t)(m0 + r) * 784 + k0 + kq * 4);
            *reinterpret_cast<float4*>(&As[r * 60 + kq * 4]) = v;
        }
        // stage B tile: 64 output-cols x 56 k (zero-pad cols >= 120)
        for (int t = tid; t < 896; t += 256) {
            int r  = t / 14;
            int kq = t - r * 14;
            int n  = n0 + r;
            float4 v;
            if (n < 120) {
                v = *reinterpret_cast<const float4*>(
                    w1 + (size_t)n * 784 + k0 + kq * 4);
            } else {
                v.x = v.y = v.z = v.w = 0.f;
            }
            *reinterpret_cast<float4*>(&Bs[r * 60 + kq * 4]) = v;
        }
        __syncthreads();

#pragma unroll
        for (int kq = 0; kq < 14; ++kq) {
            float4 a[4], bb[4];
#pragma unroll
            for (int i = 0; i < 4; ++i)
                a[i] = *reinterpret_cast<const float4*>(
                    &As[(tm + 16 * i) * 60 + kq * 4]);
#pragma unroll
            for (int j = 0; j < 4; ++j)
                bb[j] = *reinterpret_cast<const float4*>(
                    &Bs[(tn + 16 * j) * 60 + kq * 4]);
#pragma unroll
            for (int i = 0; i < 4; ++i)
#pragma unroll
                for (int j = 0; j < 4; ++j) {
                    acc[i][j] = fmaf(a[i].x, bb[j].x, acc[i][j]);
                    acc[i][j] = fmaf(a[i].y, bb[j].y, acc[i][j]);
                    acc[i][j] = fmaf(a[i].z, bb[j].z, acc[i][j]);
                    acc[i][j] = fmaf(a[i].w, bb[j].w, acc[i][j]);
                }
        }
        __syncthreads();
    }

    // epilogue: bias + relu + store
#pragma unroll
    for (int j = 0; j < 4; ++j) {
        int n = n0 + tn + 16 * j;
        if (n < 120) {
            float bias = b1[n];
#pragma unroll
            for (int i = 0; i < 4; ++i) {
                float v = acc[i][j] + bias;
                h1[(size_t)(m0 + tm + 16 * i) * 120 + n] = fmaxf(v, 0.f);
            }
        }
    }
}

// ===========================================================================
// K3: fc2+relu, fc3, hybrid head. 64 rows per block, grid = 128.
// ===========================================================================
__global__ __launch_bounds__(256) void head_kernel(
    const float* __restrict__ h1, const float* __restrict__ w2,
    const float* __restrict__ b2, const float* __restrict__ w3,
    const float* __restrict__ b3, float* __restrict__ out)
{
    __shared__ float h1s[64 * 120];   // 30 KB
    __shared__ float w2s[84 * 120];   // 40 KB
    __shared__ float h2s[64 * 84];    // 21 KB
    const int tid = threadIdx.x;
    const int m0  = blockIdx.x * 64;

    for (int t = tid; t < 1920; t += 256) {   // 64*120/4
        *reinterpret_cast<float4*>(&h1s[t * 4]) =
            *reinterpret_cast<const float4*>(h1 + (size_t)m0 * 120 + t * 4);
    }
    for (int t = tid; t < 2520; t += 256) {   // 84*120/4
        *reinterpret_cast<float4*>(&w2s[t * 4]) =
            *reinterpret_cast<const float4*>(w2 + t * 4);
    }
    __syncthreads();

    // h2 = relu(h1 @ w2^T + b2): 64 rows x 21 col-quads = 1344 items
    for (int e = tid; e < 1344; e += 256) {
        int r  = e / 21;
        int nq = e - r * 21;
        int n0 = nq * 4;
        float4 bias = *reinterpret_cast<const float4*>(b2 + n0);
        float accv[4] = {bias.x, bias.y, bias.z, bias.w};
#pragma unroll
        for (int kq = 0; kq < 30; ++kq) {
            float4 a = *reinterpret_cast<const float4*>(&h1s[r * 120 + kq * 4]);
#pragma unroll
            for (int nn = 0; nn < 4; ++nn) {
                float4 wv = *reinterpret_cast<const float4*>(
                    &w2s[(n0 + nn) * 120 + kq * 4]);
                accv[nn] = fmaf(a.x, wv.x, accv[nn]);
                accv[nn] = fmaf(a.y, wv.y, accv[nn]);
                accv[nn] = fmaf(a.z, wv.z, accv[nn]);
                accv[nn] = fmaf(a.w, wv.w, accv[nn]);
            }
        }
        float4 o;
        o.x = fmaxf(accv[0], 0.f);
        o.y = fmaxf(accv[1], 0.f);
        o.z = fmaxf(accv[2], 0.f);
        o.w = fmaxf(accv[3], 0.f);
        *reinterpret_cast<float4*>(&h2s[r * 84 + n0]) = o;
    }
    __syncthreads();

    // fc3 + head, one thread per row
    if (tid < 64) {
        int r = tid;
        float acc = b3[0];
#pragma unroll
        for (int kq = 0; kq < 21; ++kq) {
            float4 a  = *reinterpret_cast<const float4*>(&h2s[r * 84 + kq * 4]);
            float4 wv = *reinterpret_cast<const float4*>(w3 + kq * 4);
            acc = fmaf(a.x, wv.x, acc);
            acc = fmaf(a.y, wv.y, acc);
            acc = fmaf(a.z, wv.z, acc);
            acc = fmaf(a.w, wv.w, acc);
        }
        float ev = 0.5f * (1.0f + __sinf(acc));
        float pp = 1.0f / (1.0f + __expf(-ev));
        out[m0 + r]        = pp;
        out[8192 + m0 + r] = 1.0f - pp;
    }
}

// ===========================================================================
extern "C" void kernel_launch(void* const* d_in, const int* in_sizes, int n_in,
                              void* d_out, int out_size, void* d_ws, size_t ws_size,
                              hipStream_t stream)
{
    (void)in_sizes; (void)n_in; (void)out_size; (void)ws_size;
    const float* x  = (const float*)d_in[0];
    const float* U  = (const float*)d_in[1];
    const float* w1 = (const float*)d_in[2];
    const float* b1 = (const float*)d_in[3];
    const float* w2 = (const float*)d_in[4];
    const float* b2 = (const float*)d_in[5];
    const float* w3 = (const float*)d_in[6];
    const float* b3 = (const float*)d_in[7];
    float* out = (float*)d_out;

    float* feats = (float*)d_ws;                 // 8192*784 fp32 = 25.7 MB
    float* h1    = feats + (size_t)BATCH * 784;  // 8192*120 fp32 =  3.9 MB

    qfilter_kernel<<<dim3((BATCH * NPATCH) / 256), dim3(256), 0, stream>>>(x, U, feats);
    fc1_kernel<<<dim3((BATCH / 64) * 2), dim3(256), 0, stream>>>(feats, w1, b1, h1);
    head_kernel<<<dim3(BATCH / 64), dim3(256), 0, stream>>>(h1, w2, b2, w3, b3, out);
}

// Round 2
// 143.015 us; speedup vs baseline: 1.4469x; 1.4469x over previous
//
#include <hip/hip_runtime.h>
#include <hip/hip_bf16.h>
#include <math.h>

// ---------------------------------------------------------------------------
// HybridClassifier: quantum patch filter (4-qubit RY encode + fixed 16x16
// unitary + PauliZ expectations) -> fc1(784->120, bf16 MFMA)+relu
// -> fc2(120->84)+relu -> fc3(84->1) -> analytic head -> [p, 1-p].
// Batch = 8192.
// ---------------------------------------------------------------------------

#define BATCH   8192
#define NPATCH  196
#define KPAD    800     // 784 padded to multiple of 32 for 16x16x32 MFMA

typedef __attribute__((ext_vector_type(8))) short bfrag;   // 8 x bf16 (4 VGPR)
typedef __attribute__((ext_vector_type(4))) float f32x4;   // MFMA accumulator

static __device__ __forceinline__ unsigned short f2bf(float f) {
    __hip_bfloat16 h = __float2bfloat16(f);
    return __builtin_bit_cast(unsigned short, h);
}

// ===========================================================================
// K1: quantum filter. One thread per (batch, patch). Writes bf16 feats
// [8192][800] (cols 784..799 zeroed by the p==0 thread of each row).
// ===========================================================================
__global__ __launch_bounds__(256) void qfilter_kernel(
    const float* __restrict__ x, const float* __restrict__ U,
    unsigned short* __restrict__ featsB)
{
    int gid = blockIdx.x * 256 + threadIdx.x;
    if (gid >= BATCH * NPATCH) return;
    int b = gid / NPATCH;
    int p = gid - b * NPATCH;
    int pr = p / 14;
    int pc = p - pr * 14;
    const float* xr = x + b * 784 + pr * 56 + pc * 2;
    float x0 = xr[0], x1 = xr[1], x2 = xr[28], x3 = xr[29];

    float s0, c0, s1, c1, s2, c2, s3, c3;
    __sincosf(0.5f * x0, &s0, &c0);
    __sincosf(0.5f * x1, &s1, &c1);
    __sincosf(0.5f * x2, &s2, &c2);
    __sincosf(0.5f * x3, &s3, &c3);

    // psi[i8+j4+k2+l] = a0[i]a1[j]a2[k]a3[l], wire0 = MSB, a[0]=cos a[1]=sin
    float t01[4] = {c0 * c1, c0 * s1, s0 * c1, s0 * s1};
    float t23[4] = {c2 * c3, c2 * s3, s2 * c3, s2 * s3};
    float psi[16];
#pragma unroll
    for (int i = 0; i < 16; ++i) psi[i] = t01[i >> 2] * t23[i & 3];

    // phi = U @ psi ; q = phi^2 ; meas[w] = sum_i q_i * (1 - 2*bit_w(i))
    float m0 = 0.f, m1 = 0.f, m2 = 0.f, m3 = 0.f;
#pragma unroll
    for (int i = 0; i < 16; ++i) {
        float acc = 0.f;
#pragma unroll
        for (int j = 0; j < 16; ++j)
            acc = fmaf(U[i * 16 + j], psi[j], acc);  // uniform -> scalar loads
        float q = acc * acc;
        m0 += (i & 8) ? -q : q;
        m1 += (i & 4) ? -q : q;
        m2 += (i & 2) ? -q : q;
        m3 += (i & 1) ? -q : q;
    }
    ushort4 o;
    o.x = f2bf(m0); o.y = f2bf(m1); o.z = f2bf(m2); o.w = f2bf(m3);
    *reinterpret_cast<ushort4*>(featsB + (size_t)b * KPAD + p * 4) = o;

    if (p == 0) {  // zero the K-pad tail of this row (784..799), 2x16B
        uint4 z = {0u, 0u, 0u, 0u};
        *reinterpret_cast<uint4*>(featsB + (size_t)b * KPAD + 784) = z;
        *reinterpret_cast<uint4*>(featsB + (size_t)b * KPAD + 792) = z;
    }
}

// ===========================================================================
// K0: w1 (fp32 [120][784]) -> bf16 [128][800], zero-padded.
// ===========================================================================
__global__ __launch_bounds__(256) void w1prep_kernel(
    const float* __restrict__ w1, unsigned short* __restrict__ w1B)
{
    int t = blockIdx.x * 256 + threadIdx.x;
    if (t >= 128 * KPAD) return;
    int n = t / KPAD;
    int k = t - n * KPAD;
    float v = (n < 120 && k < 784) ? w1[n * 784 + k] : 0.f;
    w1B[t] = f2bf(v);
}

// ===========================================================================
// K2: fc1 via MFMA. One 64-thread wave per (16-row M-tile, 64-col N-half).
// Grid = 512 * 2 = 1024 blocks, XCD-swizzled so both N-halves of an A-panel
// share an XCD L2. No LDS, no barriers: A-frag loads are 16 rows x 64B
// contiguous (fully coalesced); w1B (200 KB) is L2-resident.
// h1 = relu(feats @ w1^T + b1), fp32 [8192][120].
// ===========================================================================
__global__ __launch_bounds__(64) void fc1_mfma_kernel(
    const unsigned short* __restrict__ featsB,
    const unsigned short* __restrict__ w1B,
    const float* __restrict__ b1, float* __restrict__ h1)
{
    int bid = blockIdx.x;
    int swz = (bid & 7) * 128 + (bid >> 3);   // bijective: 1024 % 8 == 0
    int m0  = (swz >> 1) * 16;
    int nh  = swz & 1;
    int l   = threadIdx.x;
    int row = l & 15;
    int grp = l >> 4;

    const unsigned short* aptr = featsB + (size_t)(m0 + row) * KPAD + grp * 8;
    const unsigned short* bptr = w1B + (size_t)(nh * 64 + row) * KPAD + grp * 8;

    f32x4 acc0 = {}, acc1 = {}, acc2 = {}, acc3 = {};
    for (int k0 = 0; k0 < KPAD; k0 += 32) {
        bfrag a = *reinterpret_cast<const bfrag*>(aptr + k0);
        bfrag b0 = *reinterpret_cast<const bfrag*>(bptr + 0 * 16 * KPAD + k0);
        bfrag b1f = *reinterpret_cast<const bfrag*>(bptr + 1 * 16 * KPAD + k0);
        bfrag b2 = *reinterpret_cast<const bfrag*>(bptr + 2 * 16 * KPAD + k0);
        bfrag b3 = *reinterpret_cast<const bfrag*>(bptr + 3 * 16 * KPAD + k0);
        acc0 = __builtin_amdgcn_mfma_f32_16x16x32_bf16(a, b0, acc0, 0, 0, 0);
        acc1 = __builtin_amdgcn_mfma_f32_16x16x32_bf16(a, b1f, acc1, 0, 0, 0);
        acc2 = __builtin_amdgcn_mfma_f32_16x16x32_bf16(a, b2, acc2, 0, 0, 0);
        acc3 = __builtin_amdgcn_mfma_f32_16x16x32_bf16(a, b3, acc3, 0, 0, 0);
    }

    f32x4 accs[4] = {acc0, acc1, acc2, acc3};
#pragma unroll
    for (int nj = 0; nj < 4; ++nj) {
        int col = nh * 64 + nj * 16 + row;   // C/D: col = lane&15
        if (col < 120) {
            float bias = b1[col];
#pragma unroll
            for (int r = 0; r < 4; ++r) {    // row = (lane>>4)*4 + r
                float v = accs[nj][r] + bias;
                h1[(size_t)(m0 + grp * 4 + r) * 120 + col] = fmaxf(v, 0.f);
            }
        }
    }
}

// ===========================================================================
// K3: fc2+relu, fc3, hybrid head. 64 rows per block, grid = 128.
// ===========================================================================
__global__ __launch_bounds__(256) void head_kernel(
    const float* __restrict__ h1, const float* __restrict__ w2,
    const float* __restrict__ b2, const float* __restrict__ w3,
    const float* __restrict__ b3, float* __restrict__ out)
{
    __shared__ float h1s[64 * 120];   // 30 KB
    __shared__ float w2s[84 * 120];   // 40 KB
    __shared__ float h2s[64 * 84];    // 21 KB
    const int tid = threadIdx.x;
    const int m0  = blockIdx.x * 64;

    for (int t = tid; t < 1920; t += 256) {   // 64*120/4
        *reinterpret_cast<float4*>(&h1s[t * 4]) =
            *reinterpret_cast<const float4*>(h1 + (size_t)m0 * 120 + t * 4);
    }
    for (int t = tid; t < 2520; t += 256) {   // 84*120/4
        *reinterpret_cast<float4*>(&w2s[t * 4]) =
            *reinterpret_cast<const float4*>(w2 + t * 4);
    }
    __syncthreads();

    // h2 = relu(h1 @ w2^T + b2): 64 rows x 21 col-quads = 1344 items
    for (int e = tid; e < 1344; e += 256) {
        int r  = e / 21;
        int nq = e - r * 21;
        int n0 = nq * 4;
        float4 bias = *reinterpret_cast<const float4*>(b2 + n0);
        float accv[4] = {bias.x, bias.y, bias.z, bias.w};
#pragma unroll
        for (int kq = 0; kq < 30; ++kq) {
            float4 a = *reinterpret_cast<const float4*>(&h1s[r * 120 + kq * 4]);
#pragma unroll
            for (int nn = 0; nn < 4; ++nn) {
                float4 wv = *reinterpret_cast<const float4*>(
                    &w2s[(n0 + nn) * 120 + kq * 4]);
                accv[nn] = fmaf(a.x, wv.x, accv[nn]);
                accv[nn] = fmaf(a.y, wv.y, accv[nn]);
                accv[nn] = fmaf(a.z, wv.z, accv[nn]);
                accv[nn] = fmaf(a.w, wv.w, accv[nn]);
            }
        }
        float4 o;
        o.x = fmaxf(accv[0], 0.f);
        o.y = fmaxf(accv[1], 0.f);
        o.z = fmaxf(accv[2], 0.f);
        o.w = fmaxf(accv[3], 0.f);
        *reinterpret_cast<float4*>(&h2s[r * 84 + n0]) = o;
    }
    __syncthreads();

    // fc3 + head, one thread per row
    if (tid < 64) {
        int r = tid;
        float acc = b3[0];
#pragma unroll
        for (int kq = 0; kq < 21; ++kq) {
            float4 a  = *reinterpret_cast<const float4*>(&h2s[r * 84 + kq * 4]);
            float4 wv = *reinterpret_cast<const float4*>(w3 + kq * 4);
            acc = fmaf(a.x, wv.x, acc);
            acc = fmaf(a.y, wv.y, acc);
            acc = fmaf(a.z, wv.z, acc);
            acc = fmaf(a.w, wv.w, acc);
        }
        float ev = 0.5f * (1.0f + __sinf(acc));
        float pp = 1.0f / (1.0f + __expf(-ev));
        out[m0 + r]        = pp;
        out[8192 + m0 + r] = 1.0f - pp;
    }
}

// ===========================================================================
extern "C" void kernel_launch(void* const* d_in, const int* in_sizes, int n_in,
                              void* d_out, int out_size, void* d_ws, size_t ws_size,
                              hipStream_t stream)
{
    (void)in_sizes; (void)n_in; (void)out_size; (void)ws_size;
    const float* x  = (const float*)d_in[0];
    const float* U  = (const float*)d_in[1];
    const float* w1 = (const float*)d_in[2];
    const float* b1 = (const float*)d_in[3];
    const float* w2 = (const float*)d_in[4];
    const float* b2 = (const float*)d_in[5];
    const float* w3 = (const float*)d_in[6];
    const float* b3 = (const float*)d_in[7];
    float* out = (float*)d_out;

    unsigned short* featsB = (unsigned short*)d_ws;           // 8192*800 bf16 = 13.1 MB
    unsigned short* w1B = featsB + (size_t)BATCH * KPAD;      // 128*800 bf16 = 205 KB
    float* h1 = (float*)(w1B + (size_t)128 * KPAD);           // 8192*120 fp32 = 3.9 MB

    w1prep_kernel<<<dim3((128 * KPAD + 255) / 256), dim3(256), 0, stream>>>(w1, w1B);
    qfilter_kernel<<<dim3((BATCH * NPATCH) / 256), dim3(256), 0, stream>>>(x, U, featsB);
    fc1_mfma_kernel<<<dim3(1024), dim3(64), 0, stream>>>(featsB, w1B, b1, h1);
    head_kernel<<<dim3(BATCH / 64), dim3(256), 0, stream>>>(h1, w2, b2, w3, b3, out);
}